// Round 1
// baseline (4951.649 us; speedup 1.0000x reference)
//
#include <hip/hip_runtime.h>
#include <hip/hip_fp16.h>
#include <stdint.h>

// Gated LSTM: B=64, T=2048, I=128, H=256, O=1.
// Persistent kernel: 64 WGs = 8 batch-groups x 8 N-slices (p = bid>>3).
// Each WG: 256 threads, batches g*8..g*8+7, h-outputs j = p*32..p*32+31.
// W slice lives in VGPRs as f16 MFMA B-fragments (zero per-step W traffic).
//
// R3 change (exchange path): the 8 communicating WGs of a group land on one
// XCD (bid%8 round-robin dispatch -> g = bid&7 co-locates them). Intra-XCD,
// a PLAIN store (write-through L1 -> shared XCD L2) + an sc0 load (L1-bypass,
// L2-served) is enough for tagged h exchange -- no device-scope (sc1) ops
// that round-trip the Infinity-Cache coherence point (R2's 1.7us/step).
// Placement is NOT guaranteed, so a one-time startup probe tests the fast
// path pair-wise; on failure the group falls back to R2's agent-scope
// protocol (verdict agreed through agent atomics -> no deadlock possible).
// Also: x/w are register-prefetched 2 steps ahead (2-step-unrolled loop) so
// HBM latency stays off the now-short critical path.

#define NB 64
#define NT 2048
#define NI 128
#define NH 256

#define PROBE_TAG 0x7E570001u
#define PRE_TAG   0x5EED0001u
#define VERD_TAG  0x5EED0002u

typedef _Float16 h8_t __attribute__((ext_vector_type(8)));
typedef _Float16 h4_t __attribute__((ext_vector_type(4)));
typedef float f4_t __attribute__((ext_vector_type(4)));

__device__ __forceinline__ float sigm(float x) {
  return __builtin_amdgcn_rcpf(1.f + __expf(-x));
}
__device__ __forceinline__ float tanh_f(float x) {
  return 1.f - 2.f * __builtin_amdgcn_rcpf(1.f + __expf(2.f * x));
}

// 7 L1-bypassing (sc0) L2-served loads + drain. vmcnt(0) inside the asm so
// no asm-issued load leaks past it (keeps the compiler's own vmcnt model
// sound). sc0 = L1 bypass / L2 serve; deliberately NOT sc1 (no L2 bypass).
__device__ __forceinline__ void fast_sweep7(const uint64_t* fb, const int* po,
                                            uint64_t* v) {
  asm volatile(
      "global_load_dwordx2 %0, %7, %14 sc0\n\t"
      "global_load_dwordx2 %1, %8, %14 sc0\n\t"
      "global_load_dwordx2 %2, %9, %14 sc0\n\t"
      "global_load_dwordx2 %3, %10, %14 sc0\n\t"
      "global_load_dwordx2 %4, %11, %14 sc0\n\t"
      "global_load_dwordx2 %5, %12, %14 sc0\n\t"
      "global_load_dwordx2 %6, %13, %14 sc0\n\t"
      "s_waitcnt vmcnt(0)"
      : "=&v"(v[0]), "=&v"(v[1]), "=&v"(v[2]), "=&v"(v[3]), "=&v"(v[4]),
        "=&v"(v[5]), "=&v"(v[6])
      : "v"(po[0]), "v"(po[1]), "v"(po[2]), "v"(po[3]), "v"(po[4]),
        "v"(po[5]), "v"(po[6]), "s"(fb)
      : "memory");
}

// Plain store: write-through L1 into the XCD-shared L2 (fire and forget).
__device__ __forceinline__ void fast_store(uint64_t* fb, int boff,
                                           uint64_t pay) {
  asm volatile("global_store_dwordx2 %0, %1, %2"
               :: "v"(boff), "v"(pay), "s"(fb)
               : "memory");
}

// ws layout (u64 index): [0,32768) fast exchange (2 bufs x 16384),
// [32768,65536) slow exchange (2 bufs x 16384), [65536,65600) verdict slots.
// 0xAA ws poison (tag 0xAAAAAAAA) never aliases a valid tag or PROBE/VERD.

#define STEP(T, XV, WGV) do {                                               \
  const int tt = (T);                                                       \
  if (tt > 0) {                                                             \
    unsigned need = 0x7f;                                                   \
    if (fastmode) {                                                         \
      const uint64_t* fb = exf + ((tt & 1) << 14);                          \
      while (need) {                                                        \
        uint64_t v[7];                                                      \
        fast_sweep7(fb, poff, v);                                           \
        _Pragma("unroll")                                                   \
        for (int s7 = 0; s7 < 7; ++s7)                                      \
          if ((need & (1u << s7)) &&                                        \
              (unsigned)(v[s7] >> 32) == (unsigned)tt) {                    \
            int ps = (s7 < p) ? s7 : s7 + 1;                                \
            Alds[bl][NI + ps * 32 + jj] =                                   \
                (_Float16)__uint_as_float((unsigned)v[s7]);                 \
            need &= ~(1u << s7);                                            \
          }                                                                 \
      }                                                                     \
    } else {                                                                \
      const uint64_t* base = exs + ((tt & 1) << 14);                        \
      uint64_t v[7];                                                        \
      while (need) {                                                        \
        _Pragma("unroll")                                                   \
        for (int s7 = 0; s7 < 7; ++s7)                                      \
          if (need & (1u << s7))                                            \
            v[s7] = __hip_atomic_load(base + pidx[s7], __ATOMIC_RELAXED,    \
                                      __HIP_MEMORY_SCOPE_AGENT);            \
        _Pragma("unroll")                                                   \
        for (int s7 = 0; s7 < 7; ++s7)                                      \
          if ((need & (1u << s7)) &&                                        \
              (unsigned)(v[s7] >> 32) == (unsigned)tt) {                    \
            int ps = (s7 < p) ? s7 : s7 + 1;                                \
            Alds[bl][NI + ps * 32 + jj] =                                   \
                (_Float16)__uint_as_float((unsigned)v[s7]);                 \
            need &= ~(1u << s7);                                            \
          }                                                                 \
      }                                                                     \
    }                                                                       \
  }                                                                         \
  {                                                                         \
    h4_t gx;                                                                \
    gx[0] = (_Float16)(XV[0] * sigm(WGV[0]));                               \
    gx[1] = (_Float16)(XV[1] * sigm(WGV[1]));                               \
    gx[2] = (_Float16)(XV[2] * sigm(WGV[2]));                               \
    gx[3] = (_Float16)(XV[3] * sigm(WGV[3]));                               \
    *(h4_t*)(&Alds[bl][jj * 4]) = gx;                                       \
  }                                                                         \
  if (tt + 2 < NT) {   /* prefetch 2 steps ahead; consumed next use of buf */\
    XV  = *(const f4_t*)(xd + xbase + (size_t)(tt + 2) * NI);               \
    WGV = *(const f4_t*)(w  + xbase + (size_t)(tt + 2) * NI);               \
  }                                                                         \
  __syncthreads();                       /* barrier 1: A-tile complete */   \
  {                                                                         \
    f4_t acc0 = {0.f, 0.f, 0.f, 0.f}, acc1 = {0.f, 0.f, 0.f, 0.f};         \
    _Pragma("unroll")                                                       \
    for (int kt = 0; kt < 12; ++kt) {                                       \
      h8_t af = *(const h8_t*)(&Alds[cc][kt * 32 + q * 8]);                 \
      acc0 = __builtin_amdgcn_mfma_f32_16x16x32_f16(af, wf[0][kt], acc0,    \
                                                    0, 0, 0);               \
      acc1 = __builtin_amdgcn_mfma_f32_16x16x32_f16(af, wf[1][kt], acc1,    \
                                                    0, 0, 0);               \
    }                                                                       \
    if (q < 2) {                                                            \
      _Pragma("unroll")                                                     \
      for (int r = 0; r < 4; ++r) {                                         \
        Zlds[16 * (2 * wv)     + cc][q * 4 + r] = acc0[r];                  \
        Zlds[16 * (2 * wv + 1) + cc][q * 4 + r] = acc1[r];                  \
      }                                                                     \
    }                                                                       \
  }                                                                         \
  __syncthreads();                       /* barrier 2: Z complete */        \
  {                                                                         \
    float zi = Zlds[jj * 4 + 0][bl] + bias[0];                              \
    float zf = Zlds[jj * 4 + 1][bl] + bias[1];                              \
    float zg = Zlds[jj * 4 + 2][bl] + bias[2];                              \
    float zo = Zlds[jj * 4 + 3][bl] + bias[3];                              \
    creg = sigm(zf) * creg + sigm(zi) * tanh_f(zg);                         \
    hreg = sigm(zo) * tanh_f(creg);                                         \
    uint64_t pay =                                                          \
        ((uint64_t)(unsigned)(tt + 1) << 32) | __float_as_uint(hreg);       \
    if (fastmode) {                                                         \
      fast_store(exf + (((tt + 1) & 1) << 14), myoff, pay);                 \
    } else {                                                                \
      __hip_atomic_store(exs + (((tt + 1) & 1) << 14) + myidx, pay,         \
                         __ATOMIC_RELAXED, __HIP_MEMORY_SCOPE_AGENT);       \
    }                                                                       \
    Alds[bl][NI + p * 32 + jj] = (_Float16)hreg;   /* own slice for t+1 */  \
  }                                                                         \
} while (0)

__launch_bounds__(256, 1)
__global__ void lstm_persist(
    const float* __restrict__ xd, const float* __restrict__ w,
    const float* __restrict__ W_ih, const float* __restrict__ b_ih,
    const float* __restrict__ W_hh, const float* __restrict__ b_hh,
    const float* __restrict__ W_out, const float* __restrict__ b_out,
    float* __restrict__ out, uint64_t* ex, int mode)
{
  const int bid = blockIdx.x;
  const int g = bid & 7;        // batch group (co-XCD under %8 round-robin)
  const int p = bid >> 3;       // N-slice
  const int tid = threadIdx.x;
  const int lane = tid & 63;
  const int wv = tid >> 6;      // wave 0..3

  __shared__ _Float16 Alds[16][392];
  __shared__ float Zlds[128][17];
  __shared__ int fastmode_sh;

  for (int i = tid; i < 16 * 392; i += 256) (&Alds[0][0])[i] = (_Float16)0.f;

  const int q  = lane >> 4;     // 0..3
  const int cc = lane & 15;

  // ---- W B-fragments, resident in registers ----
  h8_t wf[2][12];
  for (int nt = 0; nt < 2; ++nt) {
    int r = 16 * (2 * wv + nt) + cc;
    int R = (r & 3) * NH + p * 32 + (r >> 2);
    for (int kt = 0; kt < 12; ++kt) {
      int k = kt * 32 + q * 8;
      const float* s = (k < NI) ? (W_ih + (size_t)R * NI + k)
                                : (W_hh + (size_t)R * NH + (k - NI));
      f4_t lo = *(const f4_t*)s;
      f4_t hi = *(const f4_t*)(s + 4);
      h8_t hh;
      hh[0] = (_Float16)lo[0]; hh[1] = (_Float16)lo[1];
      hh[2] = (_Float16)lo[2]; hh[3] = (_Float16)lo[3];
      hh[4] = (_Float16)hi[0]; hh[5] = (_Float16)hi[1];
      hh[6] = (_Float16)hi[2]; hh[7] = (_Float16)hi[3];
      wf[nt][kt] = hh;
    }
  }

  const int bl = tid >> 5;      // 0..7
  const int jj = tid & 31;      // 0..31
  float bias[4];
  #pragma unroll
  for (int gate = 0; gate < 4; ++gate)
    bias[gate] = b_ih[gate * NH + p * 32 + jj] + b_hh[gate * NH + p * 32 + jj];

  int pidx[7], poff[7];
  #pragma unroll
  for (int s7 = 0; s7 < 7; ++s7) {
    int ps = (s7 < p) ? s7 : s7 + 1;
    pidx[s7] = g * 2048 + ps * 256 + bl * 32 + jj;
    poff[s7] = pidx[s7] * 8;
  }
  const int myidx = g * 2048 + p * 256 + bl * 32 + jj;
  const int myoff = myidx * 8;

  uint64_t* const exf = ex;                          // fast (intra-XCD L2)
  uint64_t* const exs = mode ? (ex + 32768) : ex;    // slow (agent scope)
  uint64_t* const exv = ex + 65536;                  // verdict slots

  // ---- startup handshake: does the fast path work for THIS placement? ----
  int fastmode = 0;
  if (mode) {
    // (1) pre-load partner lines. If sc0 didn't refresh past L1, these
    // poison the L1 and the bounded probe below times out -> slow mode.
    {
      uint64_t pv[7];
      fast_sweep7(exf, poff, pv);
      asm volatile("" :: "v"(pv[0]));
    }
    __syncthreads();
    // (2) announce "pre-loaded" on the always-correct agent channel
    if (tid == 0)
      __hip_atomic_store(exv + bid, ((uint64_t)PRE_TAG << 32) | 1u,
                         __ATOMIC_RELAXED, __HIP_MEMORY_SCOPE_AGENT);
    // (3) wait for all 8 group members (orders their pre-load before our
    // probe store -> the test genuinely exercises post-cache refresh)
    if (tid < 8) {
      uint64_t vv;
      do {
        vv = __hip_atomic_load(exv + 8 * tid + g, __ATOMIC_RELAXED,
                               __HIP_MEMORY_SCOPE_AGENT);
        unsigned tg = (unsigned)(vv >> 32);
        if (tg == PRE_TAG || tg == VERD_TAG) break;
      } while (1);
    }
    __syncthreads();
    // (4) publish probe via the fast path (plain store)
    fast_store(exf, myoff, ((uint64_t)PROBE_TAG << 32) | (unsigned)bid);
    // (5) bounded fast poll
    unsigned need = 0x7f;
    for (int sw = 0; sw < 3000 && need; ++sw) {
      uint64_t v[7];
      fast_sweep7(exf, poff, v);
      #pragma unroll
      for (int s7 = 0; s7 < 7; ++s7)
        if ((need & (1u << s7)) && (unsigned)(v[s7] >> 32) == PROBE_TAG)
          need &= ~(1u << s7);
    }
    // (6) group-wide AND of per-WG verdicts (mode must be group-uniform)
    int allok = __syncthreads_and(need == 0);
    if (tid == 0)
      __hip_atomic_store(exv + bid,
                         ((uint64_t)VERD_TAG << 32) | (unsigned)(allok ? 1 : 0),
                         __ATOMIC_RELAXED, __HIP_MEMORY_SCOPE_AGENT);
    if (tid == 0) {
      int fm = 1;
      for (int m8 = 0; m8 < 8; ++m8) {
        uint64_t vv;
        do {
          vv = __hip_atomic_load(exv + 8 * m8 + g, __ATOMIC_RELAXED,
                                 __HIP_MEMORY_SCOPE_AGENT);
        } while ((unsigned)(vv >> 32) != VERD_TAG);
        fm &= (int)((unsigned)vv & 1u);
      }
      fastmode_sh = fm;
    }
    __syncthreads();
    fastmode = fastmode_sh;
  }

  float creg = 0.f;
  float hreg = 0.f;
  const size_t xbase = ((size_t)(g * 8 + bl) * NT) * NI + jj * 4;

  // prefetch t=0, t=1 into named double-buffers (static indexing)
  f4_t xvA = *(const f4_t*)(xd + xbase);
  f4_t wgA = *(const f4_t*)(w  + xbase);
  f4_t xvB = *(const f4_t*)(xd + xbase + NI);
  f4_t wgB = *(const f4_t*)(w  + xbase + NI);

  __syncthreads();   // Alds zeros staged before first step

  for (int t = 0; t < NT; t += 2) {
    STEP(t,     xvA, wgA);
    STEP(t + 1, xvB, wgB);
  }

  // ---- output: out[b] = h_T . W_out + b_out, by p==0 WGs ----
  if (p == 0) {
    float sum = hreg * W_out[jj];          // own slice (p==0)
    unsigned need = 0x7f;
    float hv[7];
    if (fastmode) {
      while (need) {
        uint64_t v[7];
        fast_sweep7(exf, poff, v);         // tag NT lives in buf parity 0
        #pragma unroll
        for (int s7 = 0; s7 < 7; ++s7)
          if ((need & (1u << s7)) && (unsigned)(v[s7] >> 32) == (unsigned)NT) {
            hv[s7] = __uint_as_float((unsigned)v[s7]);
            need &= ~(1u << s7);
          }
      }
    } else {
      uint64_t v[7];
      while (need) {
        #pragma unroll
        for (int s7 = 0; s7 < 7; ++s7)
          if (need & (1u << s7))
            v[s7] = __hip_atomic_load(exs + pidx[s7], __ATOMIC_RELAXED,
                                      __HIP_MEMORY_SCOPE_AGENT);
        #pragma unroll
        for (int s7 = 0; s7 < 7; ++s7)
          if ((need & (1u << s7)) && (unsigned)(v[s7] >> 32) == (unsigned)NT) {
            hv[s7] = __uint_as_float((unsigned)v[s7]);
            need &= ~(1u << s7);
          }
      }
    }
    #pragma unroll
    for (int s7 = 0; s7 < 7; ++s7) {
      int ps = (s7 < p) ? s7 : s7 + 1;     // p==0 -> ps = s7+1
      sum += hv[s7] * W_out[ps * 32 + jj];
    }
    #pragma unroll
    for (int m = 16; m >= 1; m >>= 1) sum += __shfl_xor(sum, m, 64);
    if (jj == 0) out[g * 8 + bl] = sum + b_out[0];
  }
}

extern "C" void kernel_launch(void* const* d_in, const int* in_sizes, int n_in,
                              void* d_out, int out_size, void* d_ws, size_t ws_size,
                              hipStream_t stream) {
  (void)in_sizes; (void)n_in; (void)out_size;
  const float* xd    = (const float*)d_in[0];
  const float* w     = (const float*)d_in[1];
  const float* W_ih  = (const float*)d_in[2];
  const float* b_ih  = (const float*)d_in[3];
  const float* W_hh  = (const float*)d_in[4];
  const float* b_hh  = (const float*)d_in[5];
  const float* W_out = (const float*)d_in[6];
  const float* b_out = (const float*)d_in[7];
  uint64_t* ex = (uint64_t*)d_ws;
  // ws: fast ex 256 KB + slow ex 256 KB + 64 verdict slots (512 B).
  // If ws is smaller, alias slow onto fast and force slow mode (== R2).
  const size_t NEEDED = (size_t)65600 * 8;  // 524800 B
  int mode = (ws_size >= NEEDED) ? 1 : 0;
  lstm_persist<<<dim3(64), dim3(256), 0, stream>>>(
      xd, w, W_ih, b_ih, W_hh, b_hh, W_out, b_out, (float*)d_out, ex, mode);
}

// Round 2
// 3729.233 us; speedup vs baseline: 1.3278x; 1.3278x over previous
//
#include <hip/hip_runtime.h>
#include <hip/hip_fp16.h>
#include <stdint.h>

// Gated LSTM: B=64, T=2048, I=128, H=256, O=1.
// Persistent kernel: 64 WGs = 8 batch-groups x 8 N-slices.
// Each WG: 256 threads, batches g*8..g*8+7, h-outputs j = p*32..p*32+31.
// W slice lives in VGPRs as f16 MFMA B-fragments (zero per-step W traffic).
//
// R4: placement-derived grouping + L2-point atomic exchange.
//  * Each WG reads its physical XCC via s_getreg(HW_REG_XCC_ID) (HW-verified
//    on gfx950), publishes it through agent-scope atomics, and ALL WGs derive
//    (g = rank of XCC, p = rank within XCC). Groups are co-resident on one
//    XCD BY CONSTRUCTION -- no dispatch-mapping assumption (R3's failure #1).
//  * Exchange ops are TCC-point atomics without sc1: publish =
//    atomic_exchange, poll = atomic_fetch_or(slot, opaque 0). Atomics always
//    bypass L1 and, without sc1, execute at the local XCD L2 -- producer and
//    consumer rendezvous at the same physical line (kills R3's failure #2:
//    sc0-load L1-staleness). Opaque zero (asm) stops LLVM canonicalizing the
//    idempotent RMW into a plain (L1-cacheable) load.
//  * Bounded probe on the real mechanism; per-group verdict over the agent
//    channel; fallback = exact R2 protocol (separate slow buffer region).
//  * gen = fetch_add(slot)+1 tags handshake entries so 0xAA poison can never
//    alias a valid tag (R3 had poison>>8 == gen -> deadlock risk).
// Role-indexed slots (g,p,b,j) make stale cross-replay values benign: same
// slot+tag => same deterministic h value.

#define NB 64
#define NT 2048
#define NI 128
#define NH 256

typedef _Float16 h8_t __attribute__((ext_vector_type(8)));
typedef _Float16 h4_t __attribute__((ext_vector_type(4)));
typedef float f4_t __attribute__((ext_vector_type(4)));

__device__ __forceinline__ float sigm(float x) {
  return __builtin_amdgcn_rcpf(1.f + __expf(-x));
}
__device__ __forceinline__ float tanh_f(float x) {
  return 1.f - 2.f * __builtin_amdgcn_rcpf(1.f + __expf(2.f * x));
}

// ws layout (u64 index):
//   [0,32768)      fast exchange (2 parity bufs x 16384), L2-point atomics
//   [32768,65536)  slow exchange (2 parity bufs x 16384), agent scope
//   [65536,65600)  xcc table   (64)   } all tagged (gen<<8)|payload
//   [65600,65664)  verdicts    (64)   }
//   [65664,65728)  generation  (64)
// slot index within a buf: g*2048 + p*256 + b*32 + j  (role-indexed)

#define STEP(T, XV, WGV, FAST) do {                                         \
  const int tt = (T);                                                       \
  {                                                                         \
    h4_t gx;                                                                \
    gx[0] = (_Float16)(XV[0] * sigm(WGV[0]));                               \
    gx[1] = (_Float16)(XV[1] * sigm(WGV[1]));                               \
    gx[2] = (_Float16)(XV[2] * sigm(WGV[2]));                               \
    gx[3] = (_Float16)(XV[3] * sigm(WGV[3]));                               \
    *(h4_t*)(&Alds[bl][jj * 4]) = gx;                                       \
  }                                                                         \
  if (tt + 2 < NT) {   /* prefetch 2 ahead; ages under the poll below */    \
    XV  = *(const f4_t*)(xd + xbase + (size_t)(tt + 2) * NI);               \
    WGV = *(const f4_t*)(w  + xbase + (size_t)(tt + 2) * NI);               \
  }                                                                         \
  if (tt > 0) {                                                             \
    uint64_t* base = (FAST ? exf : exs) + ((tt & 1) << 14);                 \
    unsigned need = 0x7f;                                                   \
    uint64_t v[7];                                                          \
    while (need) {                                                          \
      _Pragma("unroll")                                                     \
      for (int s7 = 0; s7 < 7; ++s7)                                        \
        if (need & (1u << s7))                                              \
          v[s7] = FAST ? __hip_atomic_fetch_or(base + pidx[s7], z0,         \
                             __ATOMIC_RELAXED, __HIP_MEMORY_SCOPE_WORKGROUP)\
                       : __hip_atomic_load(base + pidx[s7], __ATOMIC_RELAXED,\
                             __HIP_MEMORY_SCOPE_AGENT);                     \
      _Pragma("unroll")                                                     \
      for (int s7 = 0; s7 < 7; ++s7)                                        \
        if ((need & (1u << s7)) &&                                          \
            (unsigned)(v[s7] >> 32) == (unsigned)tt) {                      \
          int ps = (s7 < p) ? s7 : s7 + 1;                                  \
          Alds[bl][NI + ps * 32 + jj] =                                     \
              (_Float16)__uint_as_float((unsigned)v[s7]);                   \
          need &= ~(1u << s7);                                              \
        }                                                                   \
    }                                                                       \
  }                                                                         \
  __syncthreads();                       /* barrier 1: A-tile complete */   \
  {                                                                         \
    f4_t acc0 = {0.f, 0.f, 0.f, 0.f}, acc1 = {0.f, 0.f, 0.f, 0.f};         \
    _Pragma("unroll")                                                       \
    for (int kt = 0; kt < 12; ++kt) {                                       \
      h8_t af = *(const h8_t*)(&Alds[cc][kt * 32 + q * 8]);                 \
      acc0 = __builtin_amdgcn_mfma_f32_16x16x32_f16(af, wf[0][kt], acc0,    \
                                                    0, 0, 0);               \
      acc1 = __builtin_amdgcn_mfma_f32_16x16x32_f16(af, wf[1][kt], acc1,    \
                                                    0, 0, 0);               \
    }                                                                       \
    if (q < 2) {                                                            \
      _Pragma("unroll")                                                     \
      for (int r = 0; r < 4; ++r) {                                         \
        Zlds[16 * (2 * wv)     + cc][q * 4 + r] = acc0[r];                  \
        Zlds[16 * (2 * wv + 1) + cc][q * 4 + r] = acc1[r];                  \
      }                                                                     \
    }                                                                       \
  }                                                                         \
  __syncthreads();                       /* barrier 2: Z complete */        \
  {                                                                         \
    float zi = Zlds[jj * 4 + 0][bl] + bias[0];                              \
    float zf = Zlds[jj * 4 + 1][bl] + bias[1];                              \
    float zg = Zlds[jj * 4 + 2][bl] + bias[2];                              \
    float zo = Zlds[jj * 4 + 3][bl] + bias[3];                              \
    creg = sigm(zf) * creg + sigm(zi) * tanh_f(zg);                         \
    hreg = sigm(zo) * tanh_f(creg);                                         \
    uint64_t pay =                                                          \
        ((uint64_t)(unsigned)(tt + 1) << 32) | __float_as_uint(hreg);       \
    if (FAST)                                                               \
      (void)__hip_atomic_exchange(exf + (((tt + 1) & 1) << 14) + myidx,     \
                                  pay, __ATOMIC_RELAXED,                    \
                                  __HIP_MEMORY_SCOPE_WORKGROUP);            \
    else                                                                    \
      __hip_atomic_store(exs + (((tt + 1) & 1) << 14) + myidx, pay,         \
                         __ATOMIC_RELAXED, __HIP_MEMORY_SCOPE_AGENT);       \
    Alds[bl][NI + p * 32 + jj] = (_Float16)hreg;   /* own slice for t+1 */  \
  }                                                                         \
} while (0)

__launch_bounds__(256, 1)
__global__ void lstm_persist(
    const float* __restrict__ xd, const float* __restrict__ w,
    const float* __restrict__ W_ih, const float* __restrict__ b_ih,
    const float* __restrict__ W_hh, const float* __restrict__ b_hh,
    const float* __restrict__ W_out, const float* __restrict__ b_out,
    float* __restrict__ out, uint64_t* ex, int mode)
{
  const int bid = blockIdx.x;
  const int tid = threadIdx.x;
  const int lane = tid & 63;
  const int wv = tid >> 6;      // wave 0..3
  const int q  = lane >> 4;     // 0..3
  const int cc = lane & 15;
  const int bl = tid >> 5;      // 0..7
  const int jj = tid & 31;      // 0..31

  __shared__ _Float16 Alds[16][392];
  __shared__ float Zlds[128][17];
  __shared__ int xcc_sh[64];
  __shared__ int meta_sh[4];    // bal, g, p, fastmode
  __shared__ int m_sh[8];       // group member bids (sorted)
  __shared__ uint64_t gen_sh;

  for (int i = tid; i < 16 * 392; i += 256) (&Alds[0][0])[i] = (_Float16)0.f;

  // opaque zero: compiler can't fold fetch_or(slot, z0) into a plain load
  uint64_t z0;
  asm volatile("s_mov_b64 %0, 0" : "=s"(z0));

  uint64_t* const exf = ex;                         // fast (L2-point atomics)
  uint64_t* const exs = mode ? (ex + 32768) : ex;   // slow (agent scope)
  uint64_t* const exA = ex + 65536;                 // xcc table
  uint64_t* const exB = ex + 65600;                 // verdicts
  uint64_t* const exg = ex + 65664;                 // generation

  int g, p, fastmode = 0;

  if (mode) {
    // ---- generation: uniform across WGs (identical slot histories);
    //      +1 so (gen) can never equal a poison-derived tag (poison>>8).
    if (tid == 0) {
      uint64_t old = __hip_atomic_fetch_add(exg + bid, 1, __ATOMIC_RELAXED,
                                            __HIP_MEMORY_SCOPE_AGENT);
      gen_sh = (old + 1) & 0x00FFFFFFFFFFFFFFull;
    }
    __syncthreads();
    const uint64_t gen = gen_sh;

    // ---- publish my physical XCC, gather the full table ----
    if (tid == 0) {
      unsigned x;
      asm volatile("s_getreg_b32 %0, hwreg(HW_REG_XCC_ID)" : "=s"(x));
      __hip_atomic_store(exA + bid, (gen << 8) | (uint64_t)(x & 0xffu),
                         __ATOMIC_RELAXED, __HIP_MEMORY_SCOPE_AGENT);
    }
    if (tid < 64) {
      uint64_t e;
      do {
        e = __hip_atomic_load(exA + tid, __ATOMIC_RELAXED,
                              __HIP_MEMORY_SCOPE_AGENT);
      } while ((e >> 8) != gen);
      xcc_sh[tid] = (int)(e & 0xff);
    }
    __syncthreads();

    // ---- derive grouping from placement (same table -> same result in
    //      every WG). bal: exactly 8 WGs per distinct XCC. ----
    if (tid == 0) {
      const int myx = xcc_sh[bid];
      int bal = 1;
      for (int b = 0; b < 64; ++b) {
        int c = 0;
        for (int b2 = 0; b2 < 64; ++b2) c += (xcc_sh[b2] == xcc_sh[b]);
        if (c != 8) { bal = 0; break; }
      }
      int gd = 0, rank = 0, mi = 0;
      for (int b = 0; b < 64; ++b) {
        if (xcc_sh[b] == myx) {
          if (b < bid) rank++;
          if (mi < 8) m_sh[mi++] = b;
        } else if (xcc_sh[b] < myx) {
          bool first = true;
          for (int b2 = 0; b2 < b; ++b2)
            if (xcc_sh[b2] == xcc_sh[b]) { first = false; break; }
          gd += first;
        }
      }
      meta_sh[0] = bal; meta_sh[1] = gd; meta_sh[2] = rank;
    }
    __syncthreads();
    const int bal = meta_sh[0];
    if (bal) { g = meta_sh[1]; p = meta_sh[2]; }
    else     { g = bid & 7;    p = bid >> 3;   }

    // ---- bounded probe of the actual fast mechanism ----
    if (bal) {
      const int myidx_p = g * 2048 + p * 256 + bl * 32 + jj;
      int pidx_p[7];
      #pragma unroll
      for (int s7 = 0; s7 < 7; ++s7) {
        int ps = (s7 < p) ? s7 : s7 + 1;
        pidx_p[s7] = g * 2048 + ps * 256 + bl * 32 + jj;
      }
      const unsigned ptag = 0x7E000000u | ((unsigned)gen & 0xFFFFFFu);
      (void)__hip_atomic_exchange(
          exf + myidx_p, ((uint64_t)ptag << 32) | (unsigned)bid,
          __ATOMIC_RELAXED, __HIP_MEMORY_SCOPE_WORKGROUP);
      unsigned need = 0x7f;
      for (int sw = 0; sw < 400 && need; ++sw) {
        uint64_t v[7];
        #pragma unroll
        for (int s7 = 0; s7 < 7; ++s7)
          if (need & (1u << s7))
            v[s7] = __hip_atomic_fetch_or(exf + pidx_p[s7], z0,
                                          __ATOMIC_RELAXED,
                                          __HIP_MEMORY_SCOPE_WORKGROUP);
        #pragma unroll
        for (int s7 = 0; s7 < 7; ++s7)
          if ((need & (1u << s7)) && (unsigned)(v[s7] >> 32) == ptag)
            need &= ~(1u << s7);
      }
      int allok = __syncthreads_and(need == 0);
      if (tid == 0) {
        __hip_atomic_store(exB + bid,
                           (gen << 8) | 0x40ull | (uint64_t)(allok ? 1 : 0),
                           __ATOMIC_RELAXED, __HIP_MEMORY_SCOPE_AGENT);
        int fm = 1;
        for (int k = 0; k < 8; ++k) {
          uint64_t vv;
          do {
            vv = __hip_atomic_load(exB + m_sh[k], __ATOMIC_RELAXED,
                                   __HIP_MEMORY_SCOPE_AGENT);
          } while ((vv >> 8) != gen);
          fm &= (int)(vv & 1u);
        }
        meta_sh[3] = fm;
      }
      __syncthreads();
      fastmode = meta_sh[3];
    }
  } else {
    g = bid & 7;
    p = bid >> 3;
  }

  // ---- W B-fragments, resident in registers (uses derived p) ----
  h8_t wf[2][12];
  for (int nt = 0; nt < 2; ++nt) {
    int r = 16 * (2 * wv + nt) + cc;
    int R = (r & 3) * NH + p * 32 + (r >> 2);
    for (int kt = 0; kt < 12; ++kt) {
      int k = kt * 32 + q * 8;
      const float* s = (k < NI) ? (W_ih + (size_t)R * NI + k)
                                : (W_hh + (size_t)R * NH + (k - NI));
      f4_t lo = *(const f4_t*)s;
      f4_t hi = *(const f4_t*)(s + 4);
      h8_t hh;
      hh[0] = (_Float16)lo[0]; hh[1] = (_Float16)lo[1];
      hh[2] = (_Float16)lo[2]; hh[3] = (_Float16)lo[3];
      hh[4] = (_Float16)hi[0]; hh[5] = (_Float16)hi[1];
      hh[6] = (_Float16)hi[2]; hh[7] = (_Float16)hi[3];
      wf[nt][kt] = hh;
    }
  }

  float bias[4];
  #pragma unroll
  for (int gate = 0; gate < 4; ++gate)
    bias[gate] = b_ih[gate * NH + p * 32 + jj] + b_hh[gate * NH + p * 32 + jj];

  int pidx[7];
  #pragma unroll
  for (int s7 = 0; s7 < 7; ++s7) {
    int ps = (s7 < p) ? s7 : s7 + 1;
    pidx[s7] = g * 2048 + ps * 256 + bl * 32 + jj;
  }
  const int myidx = g * 2048 + p * 256 + bl * 32 + jj;

  float creg = 0.f;
  float hreg = 0.f;
  const size_t xbase = ((size_t)(g * 8 + bl) * NT) * NI + jj * 4;

  // prefetch t=0, t=1 into named double-buffers (static indexing)
  f4_t xvA = *(const f4_t*)(xd + xbase);
  f4_t wgA = *(const f4_t*)(w  + xbase);
  f4_t xvB = *(const f4_t*)(xd + xbase + NI);
  f4_t wgB = *(const f4_t*)(w  + xbase + NI);

  __syncthreads();   // Alds zeros staged before first step

  if (fastmode) {
    for (int t = 0; t < NT; t += 2) {
      STEP(t,     xvA, wgA, 1);
      STEP(t + 1, xvB, wgB, 1);
    }
  } else {
    for (int t = 0; t < NT; t += 2) {
      STEP(t,     xvA, wgA, 0);
      STEP(t + 1, xvB, wgB, 0);
    }
  }

  // ---- output: out[b] = h_T . W_out + b_out, by p==0 WGs ----
  // h^(NT) carries tag NT in parity-0 buffer; own slice is hreg.
  if (p == 0) {
    float sum = hreg * W_out[jj];          // own slice (p==0)
    unsigned need = 0x7f;
    float hv[7];
    uint64_t v[7];
    while (need) {
      #pragma unroll
      for (int s7 = 0; s7 < 7; ++s7)
        if (need & (1u << s7))
          v[s7] = fastmode
                      ? __hip_atomic_fetch_or(exf + pidx[s7], z0,
                                              __ATOMIC_RELAXED,
                                              __HIP_MEMORY_SCOPE_WORKGROUP)
                      : __hip_atomic_load(exs + pidx[s7], __ATOMIC_RELAXED,
                                          __HIP_MEMORY_SCOPE_AGENT);
      #pragma unroll
      for (int s7 = 0; s7 < 7; ++s7)
        if ((need & (1u << s7)) && (unsigned)(v[s7] >> 32) == (unsigned)NT) {
          hv[s7] = __uint_as_float((unsigned)v[s7]);
          need &= ~(1u << s7);
        }
    }
    #pragma unroll
    for (int s7 = 0; s7 < 7; ++s7) {
      int ps = (s7 < p) ? s7 : s7 + 1;     // p==0 -> ps = s7+1
      sum += hv[s7] * W_out[ps * 32 + jj];
    }
    #pragma unroll
    for (int m = 16; m >= 1; m >>= 1) sum += __shfl_xor(sum, m, 64);
    if (jj == 0) out[g * 8 + bl] = sum + b_out[0];
  }
}

extern "C" void kernel_launch(void* const* d_in, const int* in_sizes, int n_in,
                              void* d_out, int out_size, void* d_ws, size_t ws_size,
                              hipStream_t stream) {
  (void)in_sizes; (void)n_in; (void)out_size;
  const float* xd    = (const float*)d_in[0];
  const float* w     = (const float*)d_in[1];
  const float* W_ih  = (const float*)d_in[2];
  const float* b_ih  = (const float*)d_in[3];
  const float* W_hh  = (const float*)d_in[4];
  const float* b_hh  = (const float*)d_in[5];
  const float* W_out = (const float*)d_in[6];
  const float* b_out = (const float*)d_in[7];
  uint64_t* ex = (uint64_t*)d_ws;
  // ws: fast 256 KB + slow 256 KB + 3*64 handshake slots = 525,824 B.
  // If ws is smaller: alias slow onto fast, skip handshake -> exact R2.
  const size_t NEEDED = (size_t)65728 * 8;
  int mode = (ws_size >= NEEDED) ? 1 : 0;
  lstm_persist<<<dim3(64), dim3(256), 0, stream>>>(
      xd, w, W_ih, b_ih, W_hh, b_hh, W_out, b_out, (float*)d_out, ex, mode);
}